// Round 3
// baseline (130.012 us; speedup 1.0000x reference)
//
#include <hip/hip_runtime.h>

#define TWO_PI 6.28318530717958647692f
#define SPAD(i) ((i) + ((i) >> 4))   // LDS pad: +1 float per 16 -> breaks stride-16/256 conflicts

__device__ __forceinline__ float2 cmul(float2 a, float2 b) {
    return make_float2(a.x * b.x - a.y * b.y, a.x * b.y + a.y * b.x);
}

__device__ __forceinline__ float2 twm(float2 z, float wr, float wi, float S) {
    float si = S * wi;
    return make_float2(z.x * wr - z.y * si, z.x * si + z.y * wr);
}

__device__ __forceinline__ float2 eiw(float ang, float S) {
    // e^{S*i*ang} via plain sinf/cosf (safe OCML calls, few per thread)
    return make_float2(cosf(ang), S * sinf(ang));
}

// 16-point DFT: out[n] = sum_k v[k] * exp(SIGN*2*pi*i*n*k/16), in-place.
template<int SIGN>
__device__ __forceinline__ void fft16(float2* v) {
    const float S = (float)SIGN;
    float2 t[16];
    #pragma unroll
    for (int k1 = 0; k1 < 4; ++k1) {           // 4-pt DFT over k2 (stride 4)
        float2 a = v[k1], b = v[k1 + 4], c = v[k1 + 8], d = v[k1 + 12];
        float arx = a.x + c.x, ary = a.y + c.y;
        float srx = a.x - c.x, sry = a.y - c.y;
        float brx = b.x + d.x, bry = b.y + d.y;
        float drx = b.x - d.x, dry = b.y - d.y;
        float ix = -S * dry, iy = S * drx;     // SIGN*i*(b-d)
        t[k1 * 4 + 0] = make_float2(arx + brx, ary + bry);
        t[k1 * 4 + 1] = make_float2(srx + ix, sry + iy);
        t[k1 * 4 + 2] = make_float2(arx - brx, ary - bry);
        t[k1 * 4 + 3] = make_float2(srx - ix, sry - iy);
    }
    const float c1 = 0.92387953251128674f;     // cos(pi/8)
    const float s1 = 0.38268343236508977f;     // sin(pi/8)
    const float c2 = 0.70710678118654752f;     // cos(pi/4)
    // t[k1*4+n2] *= W16^{SIGN*n2*k1}
    t[5]  = twm(t[5],  c1,  s1, S);
    t[6]  = twm(t[6],  c2,  c2, S);
    t[7]  = twm(t[7],  s1,  c1, S);
    t[9]  = twm(t[9],  c2,  c2, S);
    t[10] = twm(t[10], 0.f, 1.f, S);
    t[11] = twm(t[11], -c2, c2, S);
    t[13] = twm(t[13], s1,  c1, S);
    t[14] = twm(t[14], -c2, c2, S);
    t[15] = twm(t[15], -c1, -s1, S);
    #pragma unroll
    for (int n2 = 0; n2 < 4; ++n2) {           // 4-pt DFT over k1 (stride 4 in t)
        float2 a = t[n2], b = t[4 + n2], c = t[8 + n2], d = t[12 + n2];
        float arx = a.x + c.x, ary = a.y + c.y;
        float srx = a.x - c.x, sry = a.y - c.y;
        float brx = b.x + d.x, bry = b.y + d.y;
        float drx = b.x - d.x, dry = b.y - d.y;
        float ix = -S * dry, iy = S * drx;
        v[n2 + 0]  = make_float2(arx + brx, ary + bry);
        v[n2 + 4]  = make_float2(srx + ix, sry + iy);
        v[n2 + 8]  = make_float2(arx - brx, ary - bry);
        v[n2 + 12] = make_float2(srx - ix, sry - iy);
    }
}

// 4096-pt DFT, 256 threads, radix-16 x3 through LDS.
// Input: v[k3] = x[t + 256*k3]. Output: v[n1] = X[t + 256*n1].
// k = k1 + 16*k2 + 256*k3 ; n = n3 + 16*n2 + 256*n1.
template<int SIGN>
__device__ __forceinline__ void fft4096(float2* v, float* sre, float* sim, int t) {
    const float S = (float)SIGN;
    // ---- step 1: DFT over k3 -> n3 ; twiddle W256^{SIGN*n3*k2}
    {
        const int k1 = t & 15, k2 = t >> 4;
        fft16<SIGN>(v);
        float2 w = eiw(TWO_PI * (float)k2 * (1.0f / 256.0f), S);
        float2 cur = make_float2(1.f, 0.f);
        #pragma unroll
        for (int n3 = 1; n3 < 16; ++n3) {
            cur = cmul(cur, w);
            v[n3] = cmul(v[n3], cur);
        }
        #pragma unroll
        for (int n3 = 0; n3 < 16; ++n3) {
            int idx = k2 * 256 + k1 * 16 + n3;
            sre[SPAD(idx)] = v[n3].x;
            sim[SPAD(idx)] = v[n3].y;
        }
    }
    __syncthreads();
    // ---- step 2: DFT over k2 -> n2 ; twiddle W4096^{SIGN*(n3+16*n2)*k1}
    {
        const int n3 = t & 15, k1 = t >> 4;
        #pragma unroll
        for (int k2 = 0; k2 < 16; ++k2) {
            int idx = k2 * 256 + k1 * 16 + n3;
            v[k2] = make_float2(sre[SPAD(idx)], sim[SPAD(idx)]);
        }
        fft16<SIGN>(v);
        float2 wb  = eiw(TWO_PI * (float)(n3 * k1) * (1.0f / 4096.0f), S);
        float2 wst = eiw(TWO_PI * (float)k1 * (1.0f / 256.0f), S);
        #pragma unroll
        for (int n2 = 0; n2 < 16; ++n2) {
            v[n2] = cmul(v[n2], wb);
            wb = cmul(wb, wst);
        }
        __syncthreads();   // all reads done before any in-place overwrite
        #pragma unroll
        for (int n2 = 0; n2 < 16; ++n2) {
            int idx = k1 * 256 + n2 * 16 + n3;
            sre[SPAD(idx)] = v[n2].x;
            sim[SPAD(idx)] = v[n2].y;
        }
    }
    __syncthreads();
    // ---- step 3: DFT over k1 -> n1 ; thread t = n3 + 16*n2
    {
        #pragma unroll
        for (int k1 = 0; k1 < 16; ++k1) {
            int idx = k1 * 256 + t;            // n2*16 + n3 == t
            v[k1] = make_float2(sre[SPAD(idx)], sim[SPAD(idx)]);
        }
        fft16<SIGN>(v);
    }
}

// Stage 1: forward FFT of reflect-padded x. xh[b*2048 + k], k in [0,2048).
__global__ __launch_bounds__(256) void kfwd(const float* __restrict__ x,
                                            float2* __restrict__ xh) {
    __shared__ float sre[4352], sim[4352];
    const int t = threadIdx.x, b = blockIdx.x;
    const float* xr = x + b * 2048;
    float2 v[16];
    #pragma unroll
    for (int k3 = 0; k3 < 16; ++k3) {
        int j = t + 256 * k3 - 1024;           // reflect pad
        j = (j < 0) ? -j : ((j >= 2048) ? (4094 - j) : j);
        j &= 2047;                              // provably no-op; fault-proofing
        v[k3] = make_float2(xr[j], 0.0f);
    }
    fft4096<-1>(v, sre, sim, t);
    float2* xo = xh + b * 2048;
    #pragma unroll
    for (int n1 = 0; n1 < 8; ++n1)
        xo[t + 256 * n1] = v[n1];
}

// Stage 2: per (b,a): Re(ifft(Psih[a]*xh[b]))/4096, write n in [1024,3072).
// Output is float32 REAL PART only (harness casts complex64 ref to float32).
__global__ __launch_bounds__(256) void kinv(const float* __restrict__ Psih,
                                            const float2* __restrict__ xh,
                                            float* __restrict__ out,
                                            long long out_cap) {
    __shared__ float sre[4352], sim[4352];
    const int t = threadIdx.x;
    const int blk = blockIdx.x;
    const int a = blk & 255, b = blk >> 8;
    const float* pr = Psih + (size_t)a * 4096;
    const float2* xr = xh + (size_t)b * 2048;
    const float inv = 1.0f / 4096.0f;
    float2 v[16];
    #pragma unroll
    for (int k3 = 0; k3 < 8; ++k3) {           // spectrum zero for k >= 2048
        int ki = (t + 256 * k3) & 2047;        // provably no-op mask
        float p = pr[ki] * inv;
        float2 z = xr[ki];
        v[k3] = make_float2(p * z.x, p * z.y);
    }
    #pragma unroll
    for (int k3 = 8; k3 < 16; ++k3) v[k3] = make_float2(0.f, 0.f);
    fft4096<1>(v, sre, sim, t);
    #pragma unroll
    for (int n1 = 4; n1 < 12; ++n1) {          // n = t + 256*n1, crop [1024,3072)
        long long oi = (long long)blk * 2048 + t + 256 * (n1 - 4);
        if (oi < out_cap) out[oi] = v[n1].x;   // real part only
    }
}

// Fallback if workspace unusable: fused fwd+mul+inv per block.
__global__ __launch_bounds__(256) void kfused(const float* __restrict__ x,
                                              const float* __restrict__ Psih,
                                              float* __restrict__ out,
                                              long long out_cap) {
    __shared__ float sre[4352], sim[4352];
    const int t = threadIdx.x;
    const int blk = blockIdx.x;
    const int a = blk & 255, b = blk >> 8;
    const float* xr = x + b * 2048;
    float2 v[16];
    #pragma unroll
    for (int k3 = 0; k3 < 16; ++k3) {
        int j = t + 256 * k3 - 1024;
        j = (j < 0) ? -j : ((j >= 2048) ? (4094 - j) : j);
        j &= 2047;
        v[k3] = make_float2(xr[j], 0.0f);
    }
    fft4096<-1>(v, sre, sim, t);
    const float* pr = Psih + (size_t)a * 4096;
    const float inv = 1.0f / 4096.0f;
    #pragma unroll
    for (int n1 = 0; n1 < 8; ++n1) {
        float p = pr[(t + 256 * n1) & 4095] * inv;
        v[n1] = make_float2(p * v[n1].x, p * v[n1].y);
    }
    #pragma unroll
    for (int n1 = 8; n1 < 16; ++n1) v[n1] = make_float2(0.f, 0.f);
    __syncthreads();
    fft4096<1>(v, sre, sim, t);
    #pragma unroll
    for (int n1 = 4; n1 < 12; ++n1) {
        long long oi = (long long)blk * 2048 + t + 256 * (n1 - 4);
        if (oi < out_cap) out[oi] = v[n1].x;
    }
}

extern "C" void kernel_launch(void* const* d_in, const int* in_sizes, int n_in,
                              void* d_out, int out_size, void* d_ws, size_t ws_size,
                              hipStream_t stream) {
    const float* x = (const float*)d_in[0];
    const float* Psih = (const float*)d_in[1];
    float* out = (float*)d_out;
    const long long out_cap = (long long)out_size;   // float32 elements
    const size_t xh_bytes = (size_t)32 * 2048 * sizeof(float2);   // 512 KB
    if (ws_size >= xh_bytes && d_ws != nullptr) {
        float2* xh = (float2*)d_ws;
        kfwd<<<32, 256, 0, stream>>>(x, xh);
        kinv<<<8192, 256, 0, stream>>>(Psih, xh, out, out_cap);
    } else {
        kfused<<<8192, 256, 0, stream>>>(x, Psih, out, out_cap);
    }
}

// Round 4
// 109.816 us; speedup vs baseline: 1.1839x; 1.1839x over previous
//
#include <hip/hip_runtime.h>

#define TWO_PI 6.28318530717958647692f
#define SPAD(i) ((i) + ((i) >> 4))   // LDS pad: +1 float per 16 -> breaks stride-16/256 conflicts

__device__ __forceinline__ float2 cmul(float2 a, float2 b) {
    return make_float2(a.x * b.x - a.y * b.y, a.x * b.y + a.y * b.x);
}

__device__ __forceinline__ float2 twm(float2 z, float wr, float wi, float S) {
    float si = S * wi;
    return make_float2(z.x * wr - z.y * si, z.x * si + z.y * wr);
}

__device__ __forceinline__ float2 eiw(float ang, float S) {
    return make_float2(cosf(ang), S * sinf(ang));
}

// 16-point DFT: out[n] = sum_k v[k] * exp(SIGN*2*pi*i*n*k/16), in-place.
template<int SIGN>
__device__ __forceinline__ void fft16(float2* v) {
    const float S = (float)SIGN;
    float2 t[16];
    #pragma unroll
    for (int k1 = 0; k1 < 4; ++k1) {           // 4-pt DFT over k2 (stride 4)
        float2 a = v[k1], b = v[k1 + 4], c = v[k1 + 8], d = v[k1 + 12];
        float arx = a.x + c.x, ary = a.y + c.y;
        float srx = a.x - c.x, sry = a.y - c.y;
        float brx = b.x + d.x, bry = b.y + d.y;
        float drx = b.x - d.x, dry = b.y - d.y;
        float ix = -S * dry, iy = S * drx;     // SIGN*i*(b-d)
        t[k1 * 4 + 0] = make_float2(arx + brx, ary + bry);
        t[k1 * 4 + 1] = make_float2(srx + ix, sry + iy);
        t[k1 * 4 + 2] = make_float2(arx - brx, ary - bry);
        t[k1 * 4 + 3] = make_float2(srx - ix, sry - iy);
    }
    const float c1 = 0.92387953251128674f;     // cos(pi/8)
    const float s1 = 0.38268343236508977f;     // sin(pi/8)
    const float c2 = 0.70710678118654752f;     // cos(pi/4)
    // t[k1*4+n2] *= W16^{SIGN*n2*k1}
    t[5]  = twm(t[5],  c1,  s1, S);
    t[6]  = twm(t[6],  c2,  c2, S);
    t[7]  = twm(t[7],  s1,  c1, S);
    t[9]  = twm(t[9],  c2,  c2, S);
    t[10] = twm(t[10], 0.f, 1.f, S);
    t[11] = twm(t[11], -c2, c2, S);
    t[13] = twm(t[13], s1,  c1, S);
    t[14] = twm(t[14], -c2, c2, S);
    t[15] = twm(t[15], -c1, -s1, S);
    #pragma unroll
    for (int n2 = 0; n2 < 4; ++n2) {           // 4-pt DFT over k1 (stride 4 in t)
        float2 a = t[n2], b = t[4 + n2], c = t[8 + n2], d = t[12 + n2];
        float arx = a.x + c.x, ary = a.y + c.y;
        float srx = a.x - c.x, sry = a.y - c.y;
        float brx = b.x + d.x, bry = b.y + d.y;
        float drx = b.x - d.x, dry = b.y - d.y;
        float ix = -S * dry, iy = S * drx;
        v[n2 + 0]  = make_float2(arx + brx, ary + bry);
        v[n2 + 4]  = make_float2(srx + ix, sry + iy);
        v[n2 + 8]  = make_float2(arx - brx, ary - bry);
        v[n2 + 12] = make_float2(srx - ix, sry - iy);
    }
}

// 4096-pt DFT, 256 threads, radix-16 x3 through LDS.
// Input: v[k3] = x[t + 256*k3]. Output: v[n1] = X[t + 256*n1].
// k = k1 + 16*k2 + 256*k3 ; n = n3 + 16*n2 + 256*n1.
template<int SIGN>
__device__ __forceinline__ void fft4096(float2* v, float* sre, float* sim, int t) {
    const float S = (float)SIGN;
    // ---- step 1: DFT over k3 -> n3 ; twiddle W256^{SIGN*n3*k2}
    {
        const int k1 = t & 15, k2 = t >> 4;
        fft16<SIGN>(v);
        float2 w = eiw(TWO_PI * (float)k2 * (1.0f / 256.0f), S);
        float2 cur = make_float2(1.f, 0.f);
        #pragma unroll
        for (int n3 = 1; n3 < 16; ++n3) {
            cur = cmul(cur, w);
            v[n3] = cmul(v[n3], cur);
        }
        #pragma unroll
        for (int n3 = 0; n3 < 16; ++n3) {
            int idx = k2 * 256 + k1 * 16 + n3;
            sre[SPAD(idx)] = v[n3].x;
            sim[SPAD(idx)] = v[n3].y;
        }
    }
    __syncthreads();
    // ---- step 2: DFT over k2 -> n2 ; twiddle W4096^{SIGN*(n3+16*n2)*k1}
    {
        const int n3 = t & 15, k1 = t >> 4;
        #pragma unroll
        for (int k2 = 0; k2 < 16; ++k2) {
            int idx = k2 * 256 + k1 * 16 + n3;
            v[k2] = make_float2(sre[SPAD(idx)], sim[SPAD(idx)]);
        }
        fft16<SIGN>(v);
        float2 wb  = eiw(TWO_PI * (float)(n3 * k1) * (1.0f / 4096.0f), S);
        float2 wst = eiw(TWO_PI * (float)k1 * (1.0f / 256.0f), S);
        #pragma unroll
        for (int n2 = 0; n2 < 16; ++n2) {
            v[n2] = cmul(v[n2], wb);
            wb = cmul(wb, wst);
        }
        __syncthreads();   // all reads done before any in-place overwrite
        #pragma unroll
        for (int n2 = 0; n2 < 16; ++n2) {
            int idx = k1 * 256 + n2 * 16 + n3;
            sre[SPAD(idx)] = v[n2].x;
            sim[SPAD(idx)] = v[n2].y;
        }
    }
    __syncthreads();
    // ---- step 3: DFT over k1 -> n1 ; thread t = n3 + 16*n2
    {
        #pragma unroll
        for (int k1 = 0; k1 < 16; ++k1) {
            int idx = k1 * 256 + t;            // n2*16 + n3 == t
            v[k1] = make_float2(sre[SPAD(idx)], sim[SPAD(idx)]);
        }
        fft16<SIGN>(v);
    }
}

// Stage 1: forward FFT of reflect-padded x. xh[b*2048 + k], k in [0,2048).
__global__ __launch_bounds__(256) void kfwd(const float* __restrict__ x,
                                            float2* __restrict__ xh) {
    __shared__ float sre[4352], sim[4352];
    const int t = threadIdx.x, b = blockIdx.x;
    const float* xr = x + b * 2048;
    float2 v[16];
    #pragma unroll
    for (int k3 = 0; k3 < 16; ++k3) {
        int j = t + 256 * k3 - 1024;           // reflect pad
        j = (j < 0) ? -j : ((j >= 2048) ? (4094 - j) : j);
        j &= 2047;                              // provably no-op; fault-proofing
        v[k3] = make_float2(xr[j], 0.0f);
    }
    fft4096<-1>(v, sre, sim, t);
    float2* xo = xh + b * 2048;
    #pragma unroll
    for (int n1 = 0; n1 < 8; ++n1)
        xo[t + 256 * n1] = v[n1];
}

// Stage 2 (packed pairs): one block per (b, scale-pair). Hermitian-symmetrize
// the spectra of scales a0=2p and a1=2p+1 (their iFFTs are real = desired
// real parts), pack Z = Za + i*Zb, one complex iFFT -> row a0 in .x, a1 in .y.
// Psih[.,0] == Psih[.,2048] == 0, so DC/Nyquist terms are exactly zero.
__global__ __launch_bounds__(256) void kinv2(const float* __restrict__ Psih,
                                             const float2* __restrict__ xh,
                                             float* __restrict__ out,
                                             long long out_cap) {
    __shared__ float sre[4352], sim[4352];
    const int t = threadIdx.x;
    const int blk = blockIdx.x;                // 4096 = 32 b * 128 pairs
    const int ap = blk & 127, b = blk >> 7;
    const int a0 = ap * 2;
    const float* pa = Psih + (size_t)a0 * 4096;
    const float* pb = pa + 4096;
    const float2* xr = xh + (size_t)b * 2048;
    const float s = 0.5f / 4096.0f;            // Hermitian 1/2 * ifft 1/N
    float2 v[16];
    #pragma unroll
    for (int k3 = 0; k3 < 8; ++k3) {           // k in [0,2048): Z = s*X*(Pa+iPb)
        int k = t + 256 * k3;
        float px = pa[k] * s, py = pb[k] * s;
        float2 X = xr[k];
        v[k3] = make_float2(px * X.x - py * X.y, py * X.x + px * X.y);
    }
    #pragma unroll
    for (int k3 = 8; k3 < 16; ++k3) {          // k in [2048,4096): Z = s*conj(X[m])*(Pa[m]+iPb[m])
        int m = 4096 - (t + 256 * k3);         // m in [1,2048]
        float px = pa[m] * s, py = pb[m] * s;  // Psih row has 4096 cols; P[2048]==0
        float2 X = xr[m & 2047];               // mask no-op except m==2048 (P==0 there)
        v[k3] = make_float2(px * X.x + py * X.y, py * X.x - px * X.y);
    }
    fft4096<1>(v, sre, sim, t);
    const long long base = ((long long)b * 256 + a0) * 2048;
    #pragma unroll
    for (int n1 = 4; n1 < 12; ++n1) {          // n = t + 256*n1, crop [1024,3072)
        long long oi = base + t + 256 * (n1 - 4);
        if (oi < out_cap) out[oi] = v[n1].x;             // row a0
        long long oj = oi + 2048;
        if (oj < out_cap) out[oj] = v[n1].y;             // row a1
    }
}

// Fallback if workspace unusable: fused fwd+mul+inv, packed pairs.
// After fwd FFT of the real padded signal, thread t holds X[k], k=t+256*n1,
// and X[k]=conj(X[4096-k]) by realness -> packed multiply is uniform.
__global__ __launch_bounds__(256) void kfused2(const float* __restrict__ x,
                                               const float* __restrict__ Psih,
                                               float* __restrict__ out,
                                               long long out_cap) {
    __shared__ float sre[4352], sim[4352];
    const int t = threadIdx.x;
    const int blk = blockIdx.x;
    const int ap = blk & 127, b = blk >> 7;
    const int a0 = ap * 2;
    const float* xr = x + b * 2048;
    float2 v[16];
    #pragma unroll
    for (int k3 = 0; k3 < 16; ++k3) {
        int j = t + 256 * k3 - 1024;
        j = (j < 0) ? -j : ((j >= 2048) ? (4094 - j) : j);
        j &= 2047;
        v[k3] = make_float2(xr[j], 0.0f);
    }
    fft4096<-1>(v, sre, sim, t);
    const float* pa = Psih + (size_t)a0 * 4096;
    const float* pb = pa + 4096;
    const float s = 0.5f / 4096.0f;
    #pragma unroll
    for (int n1 = 0; n1 < 16; ++n1) {
        int k = t + 256 * n1;
        int idx = (k < 2048) ? k : (4096 - k); // in [0,2048]; P[0]=P[2048]=0
        float px = pa[idx] * s, py = pb[idx] * s;
        float2 X = v[n1];
        v[n1] = make_float2(px * X.x - py * X.y, py * X.x + px * X.y);
    }
    __syncthreads();
    fft4096<1>(v, sre, sim, t);
    const long long base = ((long long)b * 256 + a0) * 2048;
    #pragma unroll
    for (int n1 = 4; n1 < 12; ++n1) {
        long long oi = base + t + 256 * (n1 - 4);
        if (oi < out_cap) out[oi] = v[n1].x;
        long long oj = oi + 2048;
        if (oj < out_cap) out[oj] = v[n1].y;
    }
}

extern "C" void kernel_launch(void* const* d_in, const int* in_sizes, int n_in,
                              void* d_out, int out_size, void* d_ws, size_t ws_size,
                              hipStream_t stream) {
    const float* x = (const float*)d_in[0];
    const float* Psih = (const float*)d_in[1];
    float* out = (float*)d_out;
    const long long out_cap = (long long)out_size;   // float32 elements
    const size_t xh_bytes = (size_t)32 * 2048 * sizeof(float2);   // 512 KB
    if (ws_size >= xh_bytes && d_ws != nullptr) {
        float2* xh = (float2*)d_ws;
        kfwd<<<32, 256, 0, stream>>>(x, xh);
        kinv2<<<4096, 256, 0, stream>>>(Psih, xh, out, out_cap);
    } else {
        kfused2<<<4096, 256, 0, stream>>>(x, Psih, out, out_cap);
    }
}

// Round 5
// 104.291 us; speedup vs baseline: 1.2466x; 1.0530x over previous
//
#include <hip/hip_runtime.h>

#define TWO_PI 6.28318530717958647692f
// XOR-swizzle for float2 LDS array of 4096: nibble0 ^= nibble1.
// All 4 FFT access phases hit 16 bank-pairs x 4 lanes uniformly (conflict-free b64).
#define SWZ(i) ((i) ^ (((i) >> 4) & 15))

__device__ __forceinline__ float2 cmul(float2 a, float2 b) {
    return make_float2(a.x * b.x - a.y * b.y, a.x * b.y + a.y * b.x);
}

__device__ __forceinline__ float2 twm(float2 z, float wr, float wi, float S) {
    float si = S * wi;
    return make_float2(z.x * wr - z.y * si, z.x * si + z.y * wr);
}

// e^{S*i*th} for th in [0, 0.37]: Taylor, err < 2e-7 on this range.
// (max angle in this FFT decomposition is 2*pi*15/256 = 0.368)
__device__ __forceinline__ float2 eiw(float th, float S) {
    float t2 = th * th;
    float sn = th * (1.0f + t2 * (-1.0f / 6.0f + t2 * (1.0f / 120.0f)));
    float cs = 1.0f + t2 * (-0.5f + t2 * (1.0f / 24.0f + t2 * (-1.0f / 720.0f)));
    return make_float2(cs, S * sn);
}

// 16-point DFT: out[n] = sum_k v[k] * exp(SIGN*2*pi*i*n*k/16), in-place.
template<int SIGN>
__device__ __forceinline__ void fft16(float2* v) {
    const float S = (float)SIGN;
    float2 t[16];
    #pragma unroll
    for (int k1 = 0; k1 < 4; ++k1) {           // 4-pt DFT over k2 (stride 4)
        float2 a = v[k1], b = v[k1 + 4], c = v[k1 + 8], d = v[k1 + 12];
        float arx = a.x + c.x, ary = a.y + c.y;
        float srx = a.x - c.x, sry = a.y - c.y;
        float brx = b.x + d.x, bry = b.y + d.y;
        float drx = b.x - d.x, dry = b.y - d.y;
        float ix = -S * dry, iy = S * drx;     // SIGN*i*(b-d)
        t[k1 * 4 + 0] = make_float2(arx + brx, ary + bry);
        t[k1 * 4 + 1] = make_float2(srx + ix, sry + iy);
        t[k1 * 4 + 2] = make_float2(arx - brx, ary - bry);
        t[k1 * 4 + 3] = make_float2(srx - ix, sry - iy);
    }
    const float c1 = 0.92387953251128674f;     // cos(pi/8)
    const float s1 = 0.38268343236508977f;     // sin(pi/8)
    const float c2 = 0.70710678118654752f;     // cos(pi/4)
    // t[k1*4+n2] *= W16^{SIGN*n2*k1}
    t[5]  = twm(t[5],  c1,  s1, S);
    t[6]  = twm(t[6],  c2,  c2, S);
    t[7]  = twm(t[7],  s1,  c1, S);
    t[9]  = twm(t[9],  c2,  c2, S);
    t[10] = twm(t[10], 0.f, 1.f, S);
    t[11] = twm(t[11], -c2, c2, S);
    t[13] = twm(t[13], s1,  c1, S);
    t[14] = twm(t[14], -c2, c2, S);
    t[15] = twm(t[15], -c1, -s1, S);
    #pragma unroll
    for (int n2 = 0; n2 < 4; ++n2) {           // 4-pt DFT over k1 (stride 4 in t)
        float2 a = t[n2], b = t[4 + n2], c = t[8 + n2], d = t[12 + n2];
        float arx = a.x + c.x, ary = a.y + c.y;
        float srx = a.x - c.x, sry = a.y - c.y;
        float brx = b.x + d.x, bry = b.y + d.y;
        float drx = b.x - d.x, dry = b.y - d.y;
        float ix = -S * dry, iy = S * drx;
        v[n2 + 0]  = make_float2(arx + brx, ary + bry);
        v[n2 + 4]  = make_float2(srx + ix, sry + iy);
        v[n2 + 8]  = make_float2(arx - brx, ary - bry);
        v[n2 + 12] = make_float2(srx - ix, sry - iy);
    }
}

// 4096-pt DFT, 256 threads, radix-16 x3 through swizzled float2 LDS (32768 B).
// Input: v[k3] = x[t + 256*k3]. Output: v[n1] = X[t + 256*n1].
// k = k1 + 16*k2 + 256*k3 ; n = n3 + 16*n2 + 256*n1.
template<int SIGN>
__device__ __forceinline__ void fft4096(float2* v, float2* s, int t) {
    const float S = (float)SIGN;
    // ---- step 1: DFT over k3 -> n3 ; twiddle W256^{SIGN*n3*k2}
    {
        const int k1 = t & 15, k2 = t >> 4;
        fft16<SIGN>(v);
        float2 w = eiw(TWO_PI * (float)k2 * (1.0f / 256.0f), S);
        float2 cur = make_float2(1.f, 0.f);
        #pragma unroll
        for (int n3 = 1; n3 < 16; ++n3) {
            cur = cmul(cur, w);
            v[n3] = cmul(v[n3], cur);
        }
        #pragma unroll
        for (int n3 = 0; n3 < 16; ++n3)
            s[SWZ(k2 * 256 + k1 * 16 + n3)] = v[n3];
    }
    __syncthreads();
    // ---- step 2: DFT over k2 -> n2 ; twiddle W4096^{SIGN*(n3+16*n2)*k1}
    {
        const int n3 = t & 15, k1 = t >> 4;
        #pragma unroll
        for (int k2 = 0; k2 < 16; ++k2)
            v[k2] = s[SWZ(k2 * 256 + k1 * 16 + n3)];
        fft16<SIGN>(v);
        float2 wb  = eiw(TWO_PI * (float)(n3 * k1) * (1.0f / 4096.0f), S);
        float2 wst = eiw(TWO_PI * (float)k1 * (1.0f / 256.0f), S);
        #pragma unroll
        for (int n2 = 0; n2 < 16; ++n2) {
            v[n2] = cmul(v[n2], wb);
            wb = cmul(wb, wst);
        }
        __syncthreads();   // all reads done before any in-place overwrite
        #pragma unroll
        for (int n2 = 0; n2 < 16; ++n2)
            s[SWZ(k1 * 256 + n2 * 16 + n3)] = v[n2];
    }
    __syncthreads();
    // ---- step 3: DFT over k1 -> n1 ; thread t = n3 + 16*n2
    {
        #pragma unroll
        for (int k1 = 0; k1 < 16; ++k1)
            v[k1] = s[SWZ(k1 * 256 + t)];      // n2*16 + n3 == t
        fft16<SIGN>(v);
    }
}

// Stage 1: forward FFT of reflect-padded x. xh[b*2048 + k], k in [0,2048).
__global__ __launch_bounds__(256) void kfwd(const float* __restrict__ x,
                                            float2* __restrict__ xh) {
    __shared__ float2 sbuf[4096];
    const int t = threadIdx.x, b = blockIdx.x;
    const float* xr = x + b * 2048;
    float2 v[16];
    #pragma unroll
    for (int k3 = 0; k3 < 16; ++k3) {
        int j = t + 256 * k3 - 1024;           // reflect pad
        j = (j < 0) ? -j : ((j >= 2048) ? (4094 - j) : j);
        j &= 2047;                              // provably no-op; fault-proofing
        v[k3] = make_float2(xr[j], 0.0f);
    }
    fft4096<-1>(v, sbuf, t);
    float2* xo = xh + b * 2048;
    #pragma unroll
    for (int n1 = 0; n1 < 8; ++n1)
        xo[t + 256 * n1] = v[n1];
}

// Stage 2 (packed pairs): one block per (b, scale-pair). Hermitian-symmetrize
// the spectra of scales a0=2p and a1=2p+1 (their iFFTs are real = desired
// real parts), pack Z = Za + i*Zb, one complex iFFT -> row a0 in .x, a1 in .y.
// Psih[.,0] == Psih[.,2048] == 0, so DC/Nyquist terms are exactly zero.
__global__ __launch_bounds__(256) void kinv2(const float* __restrict__ Psih,
                                             const float2* __restrict__ xh,
                                             float* __restrict__ out,
                                             long long out_cap) {
    __shared__ float2 sbuf[4096];
    const int t = threadIdx.x;
    const int blk = blockIdx.x;                // 4096 = 32 b * 128 pairs
    const int ap = blk & 127, b = blk >> 7;
    const int a0 = ap * 2;
    const float* pa = Psih + (size_t)a0 * 4096;
    const float* pb = pa + 4096;
    const float2* xr = xh + (size_t)b * 2048;
    const float s = 0.5f / 4096.0f;            // Hermitian 1/2 * ifft 1/N
    float2 v[16];
    #pragma unroll
    for (int k3 = 0; k3 < 8; ++k3) {           // k in [0,2048): Z = s*X*(Pa+iPb)
        int k = t + 256 * k3;
        float px = pa[k] * s, py = pb[k] * s;
        float2 X = xr[k];
        v[k3] = make_float2(px * X.x - py * X.y, py * X.x + px * X.y);
    }
    #pragma unroll
    for (int k3 = 8; k3 < 16; ++k3) {          // k in [2048,4096): Z = s*conj(X[m])*(Pa[m]+iPb[m])
        int m = 4096 - (t + 256 * k3);         // m in [1,2048]
        float px = pa[m] * s, py = pb[m] * s;  // Psih row has 4096 cols; P[2048]==0
        float2 X = xr[m & 2047];               // mask no-op except m==2048 (P==0 there)
        v[k3] = make_float2(px * X.x + py * X.y, py * X.x - px * X.y);
    }
    fft4096<1>(v, sbuf, t);
    const long long base = ((long long)b * 256 + a0) * 2048;
    #pragma unroll
    for (int n1 = 4; n1 < 12; ++n1) {          // n = t + 256*n1, crop [1024,3072)
        long long oi = base + t + 256 * (n1 - 4);
        if (oi < out_cap) out[oi] = v[n1].x;             // row a0
        long long oj = oi + 2048;
        if (oj < out_cap) out[oj] = v[n1].y;             // row a1
    }
}

// Fallback if workspace unusable: fused fwd+mul+inv, packed pairs.
__global__ __launch_bounds__(256) void kfused2(const float* __restrict__ x,
                                               const float* __restrict__ Psih,
                                               float* __restrict__ out,
                                               long long out_cap) {
    __shared__ float2 sbuf[4096];
    const int t = threadIdx.x;
    const int blk = blockIdx.x;
    const int ap = blk & 127, b = blk >> 7;
    const int a0 = ap * 2;
    const float* xr = x + b * 2048;
    float2 v[16];
    #pragma unroll
    for (int k3 = 0; k3 < 16; ++k3) {
        int j = t + 256 * k3 - 1024;
        j = (j < 0) ? -j : ((j >= 2048) ? (4094 - j) : j);
        j &= 2047;
        v[k3] = make_float2(xr[j], 0.0f);
    }
    fft4096<-1>(v, sbuf, t);
    const float* pa = Psih + (size_t)a0 * 4096;
    const float* pb = pa + 4096;
    const float s = 0.5f / 4096.0f;
    #pragma unroll
    for (int n1 = 0; n1 < 16; ++n1) {
        int k = t + 256 * n1;
        int idx = (k < 2048) ? k : (4096 - k); // in [0,2048]; P[0]=P[2048]=0
        float px = pa[idx] * s, py = pb[idx] * s;
        float2 X = v[n1];
        v[n1] = make_float2(px * X.x - py * X.y, py * X.x + px * X.y);
    }
    __syncthreads();
    fft4096<1>(v, sbuf, t);
    const long long base = ((long long)b * 256 + a0) * 2048;
    #pragma unroll
    for (int n1 = 4; n1 < 12; ++n1) {
        long long oi = base + t + 256 * (n1 - 4);
        if (oi < out_cap) out[oi] = v[n1].x;
        long long oj = oi + 2048;
        if (oj < out_cap) out[oj] = v[n1].y;
    }
}

extern "C" void kernel_launch(void* const* d_in, const int* in_sizes, int n_in,
                              void* d_out, int out_size, void* d_ws, size_t ws_size,
                              hipStream_t stream) {
    const float* x = (const float*)d_in[0];
    const float* Psih = (const float*)d_in[1];
    float* out = (float*)d_out;
    const long long out_cap = (long long)out_size;   // float32 elements
    const size_t xh_bytes = (size_t)32 * 2048 * sizeof(float2);   // 512 KB
    if (ws_size >= xh_bytes && d_ws != nullptr) {
        float2* xh = (float2*)d_ws;
        kfwd<<<32, 256, 0, stream>>>(x, xh);
        kinv2<<<4096, 256, 0, stream>>>(Psih, xh, out, out_cap);
    } else {
        kfused2<<<4096, 256, 0, stream>>>(x, Psih, out, out_cap);
    }
}

// Round 6
// 101.745 us; speedup vs baseline: 1.2778x; 1.0250x over previous
//
#include <hip/hip_runtime.h>

#define TWO_PI 6.28318530717958647692f
// XOR-swizzle for float2 LDS array of 4096: nibble0 ^= nibble1.
// All 4 FFT access phases hit 16 bank-pairs x 4 lanes uniformly (conflict-free b64).
#define SWZ(i) ((i) ^ (((i) >> 4) & 15))

// ---- elementwise float2 helpers (two-lane form -> v_pk_* SLP-friendly) ----
__device__ __forceinline__ float2 vadd(float2 a, float2 b) { return make_float2(a.x + b.x, a.y + b.y); }
__device__ __forceinline__ float2 vsub(float2 a, float2 b) { return make_float2(a.x - b.x, a.y - b.y); }
__device__ __forceinline__ float2 iperp(float2 z) { return make_float2(-z.y, z.x); }   // i*z

// a*b = b.x*a + b.y*(i*a)  -> 2 packed FMAs
__device__ __forceinline__ float2 cmul(float2 a, float2 b) {
    float2 p = iperp(a);
    return make_float2(fmaf(b.y, p.x, b.x * a.x), fmaf(b.y, p.y, b.x * a.y));
}

// z * (wr + i*S*wi), S compile-time sign
template<int SIGN>
__device__ __forceinline__ float2 twm(float2 z, float wr, float wi) {
    float2 p = iperp(z);
    const float swi = (SIGN > 0) ? wi : -wi;
    return make_float2(fmaf(swi, p.x, wr * z.x), fmaf(swi, p.y, wr * z.y));
}

// e^{S*i*th} for th in [0, 0.37]: Taylor, err < 2e-7 on this range.
// (max angle in this FFT decomposition is 2*pi*15/256 = 0.368)
__device__ __forceinline__ float2 eiw(float th, float S) {
    float t2 = th * th;
    float sn = th * (1.0f + t2 * (-1.0f / 6.0f + t2 * (1.0f / 120.0f)));
    float cs = 1.0f + t2 * (-0.5f + t2 * (1.0f / 24.0f + t2 * (-1.0f / 720.0f)));
    return make_float2(cs, S * sn);
}

// 4-pt butterfly core: inputs a,b,c,d -> ac,as,bd,ib (ib = SIGN*i*(b-d))
template<int SIGN>
__device__ __forceinline__ void bf4core(float2 a, float2 b, float2 c, float2 d,
                                        float2& ac, float2& as, float2& bd, float2& ib) {
    ac = vadd(a, c); as = vsub(a, c);
    bd = vadd(b, d);
    float2 bs = vsub(b, d);
    ib = (SIGN > 0) ? make_float2(-bs.y, bs.x) : make_float2(bs.y, -bs.x);
}

// 16-point DFT: out[n] = sum_k v[k] * exp(SIGN*2*pi*i*n*k/16), in-place.
// OUTSEL: 0 = all outputs; 1 = only v[4..11] (q=1,2); 2 = only v[0..7] (q=0,1).
template<int SIGN, int OUTSEL>
__device__ __forceinline__ void fft16(float2* v) {
    float2 t[16];
    #pragma unroll
    for (int k1 = 0; k1 < 4; ++k1) {           // 4-pt DFT over k2 (stride 4)
        float2 ac, as, bd, ib;
        bf4core<SIGN>(v[k1], v[k1 + 4], v[k1 + 8], v[k1 + 12], ac, as, bd, ib);
        t[k1 * 4 + 0] = vadd(ac, bd);
        t[k1 * 4 + 1] = vadd(as, ib);
        t[k1 * 4 + 2] = vsub(ac, bd);
        t[k1 * 4 + 3] = vsub(as, ib);
    }
    const float c1 = 0.92387953251128674f;     // cos(pi/8)
    const float s1 = 0.38268343236508977f;     // sin(pi/8)
    const float c2 = 0.70710678118654752f;     // cos(pi/4)
    // t[k1*4+n2] *= W16^{SIGN*n2*k1}
    t[5]  = twm<SIGN>(t[5],  c1,  s1);
    t[6]  = twm<SIGN>(t[6],  c2,  c2);
    t[7]  = twm<SIGN>(t[7],  s1,  c1);
    t[9]  = twm<SIGN>(t[9],  c2,  c2);
    t[10] = twm<SIGN>(t[10], 0.f, 1.f);
    t[11] = twm<SIGN>(t[11], -c2, c2);
    t[13] = twm<SIGN>(t[13], s1,  c1);
    t[14] = twm<SIGN>(t[14], -c2, c2);
    t[15] = twm<SIGN>(t[15], -c1, -s1);
    #pragma unroll
    for (int n2 = 0; n2 < 4; ++n2) {           // 4-pt DFT over k1 (stride 4 in t)
        float2 ac, as, bd, ib;
        bf4core<SIGN>(t[n2], t[4 + n2], t[8 + n2], t[12 + n2], ac, as, bd, ib);
        if (OUTSEL != 1) v[n2 + 0]  = vadd(ac, bd);          // q=0
        v[n2 + 4]  = vadd(as, ib);                           // q=1 (always needed)
        if (OUTSEL != 2) v[n2 + 8]  = vsub(ac, bd);          // q=2
        if (OUTSEL == 0) v[n2 + 12] = vsub(as, ib);          // q=3
    }
}

// 4096-pt DFT, 256 threads, radix-16 x3 through swizzled float2 LDS (32768 B).
// Input: v[k3] = x[t + 256*k3]. Output: v[n1] = X[t + 256*n1].
// k = k1 + 16*k2 + 256*k3 ; n = n3 + 16*n2 + 256*n1.
// OUTSEL prunes the final stage only (which n1 are produced).
template<int SIGN, int OUTSEL>
__device__ __forceinline__ void fft4096(float2* v, float2* s, int t) {
    const float S = (float)SIGN;
    // ---- step 1: DFT over k3 -> n3 ; twiddle W256^{SIGN*n3*k2}
    {
        const int k1 = t & 15, k2 = t >> 4;
        fft16<SIGN, 0>(v);
        float2 w = eiw(TWO_PI * (float)k2 * (1.0f / 256.0f), S);
        float2 cur = make_float2(1.f, 0.f);
        #pragma unroll
        for (int n3 = 1; n3 < 16; ++n3) {
            cur = cmul(cur, w);
            v[n3] = cmul(v[n3], cur);
        }
        #pragma unroll
        for (int n3 = 0; n3 < 16; ++n3)
            s[SWZ(k2 * 256 + k1 * 16 + n3)] = v[n3];
    }
    __syncthreads();
    // ---- step 2: DFT over k2 -> n2 ; twiddle W4096^{SIGN*(n3+16*n2)*k1}
    {
        const int n3 = t & 15, k1 = t >> 4;
        #pragma unroll
        for (int k2 = 0; k2 < 16; ++k2)
            v[k2] = s[SWZ(k2 * 256 + k1 * 16 + n3)];
        fft16<SIGN, 0>(v);
        float2 wb  = eiw(TWO_PI * (float)(n3 * k1) * (1.0f / 4096.0f), S);
        float2 wst = eiw(TWO_PI * (float)k1 * (1.0f / 256.0f), S);
        #pragma unroll
        for (int n2 = 0; n2 < 16; ++n2) {
            v[n2] = cmul(v[n2], wb);
            wb = cmul(wb, wst);
        }
        __syncthreads();   // all reads done before any in-place overwrite
        #pragma unroll
        for (int n2 = 0; n2 < 16; ++n2)
            s[SWZ(k1 * 256 + n2 * 16 + n3)] = v[n2];
    }
    __syncthreads();
    // ---- step 3: DFT over k1 -> n1 ; thread t = n3 + 16*n2
    {
        #pragma unroll
        for (int k1 = 0; k1 < 16; ++k1)
            v[k1] = s[SWZ(k1 * 256 + t)];      // n2*16 + n3 == t
        fft16<SIGN, OUTSEL>(v);
    }
}

// Stage 1: forward FFT of reflect-padded x. xh[b*2048 + k], k in [0,2048).
// Only n1 in [0,8) needed -> OUTSEL=2 prune.
__global__ __launch_bounds__(256) void kfwd(const float* __restrict__ x,
                                            float2* __restrict__ xh) {
    __shared__ float2 sbuf[4096];
    const int t = threadIdx.x, b = blockIdx.x;
    const float* xr = x + b * 2048;
    float2 v[16];
    #pragma unroll
    for (int k3 = 0; k3 < 16; ++k3) {
        int j = t + 256 * k3 - 1024;           // reflect pad
        j = (j < 0) ? -j : ((j >= 2048) ? (4094 - j) : j);
        j &= 2047;                              // provably no-op; fault-proofing
        v[k3] = make_float2(xr[j], 0.0f);
    }
    fft4096<-1, 2>(v, sbuf, t);
    float2* xo = xh + b * 2048;
    #pragma unroll
    for (int n1 = 0; n1 < 8; ++n1)
        xo[t + 256 * n1] = v[n1];
}

// Stage 2 (packed pairs): one block per (b, scale-pair). Hermitian-symmetrize
// the spectra of scales a0=2p and a1=2p+1 (their iFFTs are real = desired
// real parts), pack Z = Za + i*Zb, one complex iFFT -> row a0 in .x, a1 in .y.
// Psih[.,0] == Psih[.,2048] == 0, so DC/Nyquist terms are exactly zero.
// Only n1 in [4,12) (crop) needed -> OUTSEL=1 prune.
__global__ __launch_bounds__(256) void kinv2(const float* __restrict__ Psih,
                                             const float2* __restrict__ xh,
                                             float* __restrict__ out,
                                             long long out_cap) {
    __shared__ float2 sbuf[4096];
    const int t = threadIdx.x;
    const int blk = blockIdx.x;                // 4096 = 32 b * 128 pairs
    const int ap = blk & 127, b = blk >> 7;
    const int a0 = ap * 2;
    const float* pa = Psih + (size_t)a0 * 4096;
    const float* pb = pa + 4096;
    const float2* xr = xh + (size_t)b * 2048;
    const float s = 0.5f / 4096.0f;            // Hermitian 1/2 * ifft 1/N
    float2 v[16];
    #pragma unroll
    for (int k3 = 0; k3 < 8; ++k3) {           // k in [0,2048): Z = s*X*(Pa+iPb)
        int k = t + 256 * k3;
        float px = pa[k] * s, py = pb[k] * s;
        float2 X = xr[k];
        v[k3] = make_float2(px * X.x - py * X.y, py * X.x + px * X.y);
    }
    #pragma unroll
    for (int k3 = 8; k3 < 16; ++k3) {          // k in [2048,4096): Z = s*conj(X[m])*(Pa[m]+iPb[m])
        int m = 4096 - (t + 256 * k3);         // m in [1,2048]
        float px = pa[m] * s, py = pb[m] * s;  // Psih row has 4096 cols; P[2048]==0
        float2 X = xr[m & 2047];               // mask no-op except m==2048 (P==0 there)
        v[k3] = make_float2(px * X.x + py * X.y, py * X.x - px * X.y);
    }
    fft4096<1, 1>(v, sbuf, t);
    const long long base = ((long long)b * 256 + a0) * 2048;
    #pragma unroll
    for (int n1 = 4; n1 < 12; ++n1) {          // n = t + 256*n1, crop [1024,3072)
        long long oi = base + t + 256 * (n1 - 4);
        if (oi < out_cap) out[oi] = v[n1].x;             // row a0
        long long oj = oi + 2048;
        if (oj < out_cap) out[oj] = v[n1].y;             // row a1
    }
}

// Fallback if workspace unusable: fused fwd+mul+inv, packed pairs.
__global__ __launch_bounds__(256) void kfused2(const float* __restrict__ x,
                                               const float* __restrict__ Psih,
                                               float* __restrict__ out,
                                               long long out_cap) {
    __shared__ float2 sbuf[4096];
    const int t = threadIdx.x;
    const int blk = blockIdx.x;
    const int ap = blk & 127, b = blk >> 7;
    const int a0 = ap * 2;
    const float* xr = x + b * 2048;
    float2 v[16];
    #pragma unroll
    for (int k3 = 0; k3 < 16; ++k3) {
        int j = t + 256 * k3 - 1024;
        j = (j < 0) ? -j : ((j >= 2048) ? (4094 - j) : j);
        j &= 2047;
        v[k3] = make_float2(xr[j], 0.0f);
    }
    fft4096<-1, 0>(v, sbuf, t);                // full spectrum needed here
    const float* pa = Psih + (size_t)a0 * 4096;
    const float* pb = pa + 4096;
    const float s = 0.5f / 4096.0f;
    #pragma unroll
    for (int n1 = 0; n1 < 16; ++n1) {
        int k = t + 256 * n1;
        int idx = (k < 2048) ? k : (4096 - k); // in [0,2048]; P[0]=P[2048]=0
        float px = pa[idx] * s, py = pb[idx] * s;
        float2 X = v[n1];
        v[n1] = make_float2(px * X.x - py * X.y, py * X.x + px * X.y);
    }
    __syncthreads();
    fft4096<1, 1>(v, sbuf, t);
    const long long base = ((long long)b * 256 + a0) * 2048;
    #pragma unroll
    for (int n1 = 4; n1 < 12; ++n1) {
        long long oi = base + t + 256 * (n1 - 4);
        if (oi < out_cap) out[oi] = v[n1].x;
        long long oj = oi + 2048;
        if (oj < out_cap) out[oj] = v[n1].y;
    }
}

extern "C" void kernel_launch(void* const* d_in, const int* in_sizes, int n_in,
                              void* d_out, int out_size, void* d_ws, size_t ws_size,
                              hipStream_t stream) {
    const float* x = (const float*)d_in[0];
    const float* Psih = (const float*)d_in[1];
    float* out = (float*)d_out;
    const long long out_cap = (long long)out_size;   // float32 elements
    const size_t xh_bytes = (size_t)32 * 2048 * sizeof(float2);   // 512 KB
    if (ws_size >= xh_bytes && d_ws != nullptr) {
        float2* xh = (float2*)d_ws;
        kfwd<<<32, 256, 0, stream>>>(x, xh);
        kinv2<<<4096, 256, 0, stream>>>(Psih, xh, out, out_cap);
    } else {
        kfused2<<<4096, 256, 0, stream>>>(x, Psih, out, out_cap);
    }
}